// Round 1
// 56.127 us; speedup vs baseline: 1.0063x; 1.0063x over previous
//
#include <hip/hip_runtime.h>

// B=64, N=1024; token_span is a runtime scalar input (15 in the reference).
// start_position[b,i] = start[b,i] * max(end[b, i..min(i+span,N-1)])
// end_position[b,j]   = end[b,j]   * max(start[b, max(0,j-span)..j])
// Valid because prob >= 0 (uniform [0,1)): the banded outer-product row max
// factorizes into value * window-max, and the window always contains diff=0.
//
// This version: NO LDS, NO barrier. Input is 512 KB (L2-resident; per-row
// working set is 8 KB, L1-resident). Each loop iteration is a wave-wide read
// of 64 contiguous floats (256 B, coalesced) that overlaps the previous
// iteration's lines -> L1 hits. Window indices are CLAMPED (min/max) instead
// of bounds-checked: the clamped element is always inside the valid window,
// so the loop trip count is a wave-uniform `span` with zero divergence.

#define NCOLS 1024

__global__ __launch_bounds__(256) void banded_span_kernel(
    const float* __restrict__ prob,   // (B, 2N) row-major
    const int*   __restrict__ span_p, // scalar
    float* __restrict__ out,          // [B*N start_position | B*N end_position]
    int B)
{
    const int span = *span_p;
    const int b    = blockIdx.x >> 2;          // 4 blocks per row
    const int k    = ((blockIdx.x & 3) << 8) | threadIdx.x;  // global column

    const float* __restrict__ row_start = prob + (size_t)b * (2 * NCOLS);
    const float* __restrict__ row_end   = row_start + NCOLS;

    const float sv = row_start[k];
    const float ev = row_end[k];

    float m_end   = ev;   // max over end[k .. min(k+span, N-1)]
    float m_start = sv;   // max over start[max(0, k-span) .. k]

    for (int j = 1; j <= span; ++j) {
        // Clamped index stays inside the valid window (window includes the
        // edge element), so re-reading the edge is a harmless duplicate max.
        m_end   = fmaxf(m_end,   row_end[min(k + j, NCOLS - 1)]);
        m_start = fmaxf(m_start, row_start[max(k - j, 0)]);
    }

    const int base = b * NCOLS + k;
    out[base]             = sv * m_end;    // start_position
    out[B * NCOLS + base] = ev * m_start;  // end_position
}

extern "C" void kernel_launch(void* const* d_in, const int* in_sizes, int n_in,
                              void* d_out, int out_size, void* d_ws, size_t ws_size,
                              hipStream_t stream) {
    const float* prob = (const float*)d_in[0];
    const int* span   = (const int*)d_in[1];
    float* out        = (float*)d_out;

    const int B = in_sizes[0] / (2 * NCOLS);  // 64
    const int grid = B * (NCOLS / 256);       // 256 blocks, one 256-col chunk each

    banded_span_kernel<<<grid, 256, 0, stream>>>(prob, span, out, B);
}